// Round 9
// baseline (510.954 us; speedup 1.0000x reference)
//
#include <hip/hip_runtime.h>

// ---------------------------------------------------------------------------
// AML_TGNN: segment-mean over edges -> folded (msg-linear + GRU(h0=0)) -> cls
//
// R9 = ABLATION ROUND. accum (184us) does 32M random gathers AND 32M LDS u64
// atomics; all interventions so far (occupancy, ILP, sc0, glds) left both
// untouched and moved nothing. This round isolates them:
//   tgnn_accum_kernel : control (R7 path, real output)          ~184us
//   tgnn_accum_ng     : NO GATHER (payload = record bits), LDS atomics kept
//   tgnn_accum_y      : NO LDS ATOMICS (xor reg sink), gathers kept
// Both ablations run the full 32M workload and dump into d_out, which
// merge_node overwrites entirely afterward -> output stays correct.
// Readout via top-5 names + total dur (pre-committed in journal).
// ---------------------------------------------------------------------------

#define NBKT        256
#define BKT_SHIFT   12
#define DLOW_MASK   4095u
#define BKT_CAP     139264u
#define CHUNK       16384
#define BIN_THREADS 512
#define ACC_THREADS 1024
#define SPLIT       2
#define BKT_RANGE   4096
#define NODE_SPACE  (NBKT * BKT_RANGE)

__device__ __forceinline__ unsigned long long expand_pkt(unsigned q)
{
    return (1ull << 52) | ((unsigned long long)(q >> 16) << 26)
                        | (unsigned long long)(q & 0xFFFFu);
}

__device__ __forceinline__ unsigned gather_sc0(const unsigned* p)
{
    return __hip_atomic_load(p, __ATOMIC_RELAXED, __HIP_MEMORY_SCOPE_AGENT);
}

// ---------------------------------------------------------------- prep -----
__global__ __launch_bounds__(64) void tgnn_prep_kernel(
    const float* __restrict__ W_msg, const float* __restrict__ b_msg,
    const float* __restrict__ W_ih,  const float* __restrict__ b_ih,
    const float* __restrict__ b_hh,  const float* __restrict__ W_cls,
    const float* __restrict__ b_cls, float* __restrict__ P)
{
    int j = threadIdx.x;
    if (j < 48) {
        float a0 = 0.f, a1 = 0.f, dd = 0.f;
        #pragma unroll
        for (int k = 0; k < 16; ++k) {
            float w = W_ih[j * 16 + k];
            a0 += w * W_msg[k * 2 + 0];
            a1 += w * W_msg[k * 2 + 1];
            dd += w * b_msg[k];
        }
        dd += b_ih[j];
        P[j]      = a0;
        P[48 + j] = a1;
        if (j < 16)      P[96 + j]         = dd + b_hh[j];
        else if (j < 32) P[112 + (j - 16)] = dd + b_hh[j];
        else             P[128 + (j - 32)] = dd;
    }
    if (j < 16) {
        P[144 + j] = b_hh[32 + j];
        P[160 + j] = W_cls[j];
        P[176 + j] = W_cls[16 + j];
    }
    if (j == 0) { P[192] = b_cls[0]; P[193] = b_cls[1]; }
}

// --------------------------------------------------------------- quant -----
__global__ __launch_bounds__(256) void tgnn_quant_kernel(
    const float2* __restrict__ nf, unsigned* __restrict__ qnf, int n)
{
    int i = blockIdx.x * blockDim.x + threadIdx.x;
    if (i >= n) return;
    float2 f = nf[i];
    float x = fminf(fmaxf(f.x, -7.9f), 7.9f);
    float y = fminf(fmaxf(f.y, -7.9f), 7.9f);
    unsigned qx = (unsigned)fmaf(x, 4096.0f, 32768.5f);
    unsigned qy = (unsigned)fmaf(y, 4096.0f, 32768.5f);
    qnf[i] = qx | (qy << 16);
}

// --------------------------------------------------------- cursor init -----
__global__ __launch_bounds__(256) void tgnn_cursor_init(unsigned* __restrict__ cursor)
{
    int b = threadIdx.x;
    cursor[b] = (unsigned)b * BKT_CAP;
}

// ----------------------------------------------------------------- bin -----
__global__ __launch_bounds__(BIN_THREADS) void tgnn_bin_kernel(
    const int* __restrict__ src, const int* __restrict__ dst,
    const unsigned* __restrict__ qnf,
    unsigned* __restrict__ rec, unsigned* __restrict__ cursor,
    unsigned long long* __restrict__ partial0,
    int n_edges)
{
    __shared__ unsigned cnt[NBKT];
    __shared__ unsigned pos[NBKT];
    __shared__ unsigned scur[NBKT];
    __shared__ unsigned gbase[NBKT];
    __shared__ unsigned stage[CHUNK];   // 64 KB

    int t  = threadIdx.x;
    int e0 = blockIdx.x * CHUNK;
    int ne = n_edges - e0;
    if (ne <= 0) return;
    if (ne > CHUNK) ne = CHUNK;
    int nv4 = (ne + 3) >> 2;

    const int4* s4p = (const int4*)(src + e0);
    const int4* d4p = (const int4*)(dst + e0);

    int4 dr[8], sr[8];
    #pragma unroll
    for (int j = 0; j < 8; ++j) {
        int i4 = j * BIN_THREADS + t;
        if (i4 < nv4) { dr[j] = d4p[i4]; sr[j] = s4p[i4]; }
    }

    if (t < NBKT) cnt[t] = 0;
    __syncthreads();

    #pragma unroll
    for (int j = 0; j < 8; ++j) {
        int base = 4 * (j * BIN_THREADS + t);
        if (base < ne) {
            int lim = ne - base;
            int dv[4] = { dr[j].x, dr[j].y, dr[j].z, dr[j].w };
            #pragma unroll
            for (int c = 0; c < 4; ++c)
                if (c < lim) atomicAdd(&cnt[((unsigned)dv[c]) >> BKT_SHIFT], 1u);
        }
    }
    __syncthreads();

    if (t < NBKT) pos[t] = cnt[t];
    __syncthreads();
    #pragma unroll
    for (int off = 1; off < NBKT; off <<= 1) {
        unsigned v = 0, a = 0;
        if (t < NBKT) { v = pos[t]; a = (t >= off) ? pos[t - off] : 0u; }
        __syncthreads();
        if (t < NBKT) pos[t] = v + a;
        __syncthreads();
    }
    if (t < NBKT) {
        unsigned myCnt  = cnt[t];
        unsigned myBase = pos[t] - myCnt;
        scur[t] = myBase;
        pos[t]  = myBase;
        gbase[t] = myCnt ? atomicAdd(&cursor[t], myCnt) : 0u;
    }
    __syncthreads();

    #pragma unroll
    for (int j = 0; j < 8; ++j) {
        int base = 4 * (j * BIN_THREADS + t);
        if (base < ne) {
            int lim = ne - base;
            int dv[4] = { dr[j].x, dr[j].y, dr[j].z, dr[j].w };
            int sv[4] = { sr[j].x, sr[j].y, sr[j].z, sr[j].w };
            #pragma unroll
            for (int c = 0; c < 4; ++c) if (c < lim) {
                unsigned d = (unsigned)dv[c];
                unsigned b = d >> BKT_SHIFT;
                unsigned p = atomicAdd(&scur[b], 1u);
                stage[p] = (unsigned)sv[c] | ((d & DLOW_MASK) << 20);
            }
        }
    }
    __syncthreads();

    int wave = t >> 6, lane = t & 63;
    for (int b = wave; b < NBKT; b += BIN_THREADS / 64) {
        unsigned n = cnt[b];
        if (!n) continue;
        unsigned sb = pos[b];
        unsigned gb = gbase[b];
        unsigned capEnd = (unsigned)(b + 1) * BKT_CAP;
        for (unsigned i = lane; i < n; i += 64) {
            unsigned r = stage[sb + i];
            unsigned slot = gb + i;
            if (slot < capEnd) {
                rec[slot] = r;
            } else {
                unsigned node = ((unsigned)b << BKT_SHIFT) | (r >> 20);
                atomicAdd(&partial0[node], expand_pkt(qnf[r & 0xFFFFFu]));
            }
        }
    }
}

// ------------------------------------------------ accum (control, real) -----
__global__ __launch_bounds__(ACC_THREADS) void tgnn_accum_kernel(
    const unsigned* __restrict__ qnf,
    const unsigned* __restrict__ rec,
    const unsigned* __restrict__ cursor,
    unsigned long long* __restrict__ partial)
{
    __shared__ unsigned long long acc[BKT_RANGE];
    int b = blockIdx.x >> 1;
    int s = blockIdx.x & 1;
    int t = threadIdx.x;

    unsigned count = cursor[b] - (unsigned)b * BKT_CAP;
    if (count > BKT_CAP) count = BKT_CAP;
    unsigned mid = (count >> 1) & ~3u;
    unsigned i0 = s ? mid : 0u;
    unsigned i1 = s ? count : mid;

    unsigned long long* pb = partial + (size_t)s * NODE_SPACE + (size_t)b * BKT_RANGE;
    if (s == 0) {
        #pragma unroll
        for (int k = 0; k < BKT_RANGE / ACC_THREADS; ++k)
            acc[k * ACC_THREADS + t] = pb[k * ACC_THREADS + t];
    } else {
        #pragma unroll
        for (int k = 0; k < BKT_RANGE / ACC_THREADS; ++k)
            acc[k * ACC_THREADS + t] = 0ull;
    }
    __syncthreads();

    const unsigned* rb  = rec + (size_t)b * BKT_CAP;
    const int4*     rb4 = (const int4*)rb;

    unsigned v0 = i0 >> 2;
    unsigned v1 = i1 >> 2;
    unsigned v  = v0 + t;

    for (; v + ACC_THREADS < v1; v += 2 * ACC_THREADS) {
        int4 ra = rb4[v];
        int4 rc = rb4[v + ACC_THREADS];
        unsigned a0 = (unsigned)ra.x, a1 = (unsigned)ra.y;
        unsigned a2 = (unsigned)ra.z, a3 = (unsigned)ra.w;
        unsigned c0 = (unsigned)rc.x, c1 = (unsigned)rc.y;
        unsigned c2 = (unsigned)rc.z, c3 = (unsigned)rc.w;
        unsigned qa0 = gather_sc0(qnf + (a0 & 0xFFFFFu));
        unsigned qa1 = gather_sc0(qnf + (a1 & 0xFFFFFu));
        unsigned qa2 = gather_sc0(qnf + (a2 & 0xFFFFFu));
        unsigned qa3 = gather_sc0(qnf + (a3 & 0xFFFFFu));
        unsigned qc0 = gather_sc0(qnf + (c0 & 0xFFFFFu));
        unsigned qc1 = gather_sc0(qnf + (c1 & 0xFFFFFu));
        unsigned qc2 = gather_sc0(qnf + (c2 & 0xFFFFFu));
        unsigned qc3 = gather_sc0(qnf + (c3 & 0xFFFFFu));
        atomicAdd(&acc[a0 >> 20], expand_pkt(qa0));
        atomicAdd(&acc[a1 >> 20], expand_pkt(qa1));
        atomicAdd(&acc[a2 >> 20], expand_pkt(qa2));
        atomicAdd(&acc[a3 >> 20], expand_pkt(qa3));
        atomicAdd(&acc[c0 >> 20], expand_pkt(qc0));
        atomicAdd(&acc[c1 >> 20], expand_pkt(qc1));
        atomicAdd(&acc[c2 >> 20], expand_pkt(qc2));
        atomicAdd(&acc[c3 >> 20], expand_pkt(qc3));
    }
    for (; v < v1; v += ACC_THREADS) {
        int4 ra = rb4[v];
        unsigned a0 = (unsigned)ra.x, a1 = (unsigned)ra.y;
        unsigned a2 = (unsigned)ra.z, a3 = (unsigned)ra.w;
        unsigned qa0 = gather_sc0(qnf + (a0 & 0xFFFFFu));
        unsigned qa1 = gather_sc0(qnf + (a1 & 0xFFFFFu));
        unsigned qa2 = gather_sc0(qnf + (a2 & 0xFFFFFu));
        unsigned qa3 = gather_sc0(qnf + (a3 & 0xFFFFFu));
        atomicAdd(&acc[a0 >> 20], expand_pkt(qa0));
        atomicAdd(&acc[a1 >> 20], expand_pkt(qa1));
        atomicAdd(&acc[a2 >> 20], expand_pkt(qa2));
        atomicAdd(&acc[a3 >> 20], expand_pkt(qa3));
    }
    for (unsigned i = (v1 << 2) + t; i < i1; i += ACC_THREADS) {
        unsigned r = rb[i];
        atomicAdd(&acc[r >> 20], expand_pkt(gather_sc0(qnf + (r & 0xFFFFFu))));
    }
    __syncthreads();

    #pragma unroll
    for (int k = 0; k < BKT_RANGE / ACC_THREADS; ++k)
        pb[k * ACC_THREADS + t] = acc[k * ACC_THREADS + t];
}

// ------------------------ ABLATION 1: no gather, LDS atomics kept (ng) -----
__global__ __launch_bounds__(ACC_THREADS) void tgnn_accum_ng(
    const unsigned* __restrict__ rec,
    const unsigned* __restrict__ cursor,
    unsigned long long* __restrict__ dump)   // d_out sink, overwritten later
{
    __shared__ unsigned long long acc[BKT_RANGE];
    int b = blockIdx.x >> 1;
    int s = blockIdx.x & 1;
    int t = threadIdx.x;

    unsigned count = cursor[b] - (unsigned)b * BKT_CAP;
    if (count > BKT_CAP) count = BKT_CAP;
    unsigned mid = (count >> 1) & ~3u;
    unsigned i0 = s ? mid : 0u;
    unsigned i1 = s ? count : mid;

    #pragma unroll
    for (int k = 0; k < BKT_RANGE / ACC_THREADS; ++k)
        acc[k * ACC_THREADS + t] = 0ull;
    __syncthreads();

    const unsigned* rb  = rec + (size_t)b * BKT_CAP;
    const int4*     rb4 = (const int4*)rb;

    unsigned v0 = i0 >> 2;
    unsigned v1 = i1 >> 2;
    unsigned v  = v0 + t;

    for (; v + ACC_THREADS < v1; v += 2 * ACC_THREADS) {
        int4 ra = rb4[v];
        int4 rc = rb4[v + ACC_THREADS];
        unsigned a0 = (unsigned)ra.x, a1 = (unsigned)ra.y;
        unsigned a2 = (unsigned)ra.z, a3 = (unsigned)ra.w;
        unsigned c0 = (unsigned)rc.x, c1 = (unsigned)rc.y;
        unsigned c2 = (unsigned)rc.z, c3 = (unsigned)rc.w;
        atomicAdd(&acc[a0 >> 20], expand_pkt(a0));   // payload = record bits
        atomicAdd(&acc[a1 >> 20], expand_pkt(a1));
        atomicAdd(&acc[a2 >> 20], expand_pkt(a2));
        atomicAdd(&acc[a3 >> 20], expand_pkt(a3));
        atomicAdd(&acc[c0 >> 20], expand_pkt(c0));
        atomicAdd(&acc[c1 >> 20], expand_pkt(c1));
        atomicAdd(&acc[c2 >> 20], expand_pkt(c2));
        atomicAdd(&acc[c3 >> 20], expand_pkt(c3));
    }
    for (; v < v1; v += ACC_THREADS) {
        int4 ra = rb4[v];
        unsigned a0 = (unsigned)ra.x, a1 = (unsigned)ra.y;
        unsigned a2 = (unsigned)ra.z, a3 = (unsigned)ra.w;
        atomicAdd(&acc[a0 >> 20], expand_pkt(a0));
        atomicAdd(&acc[a1 >> 20], expand_pkt(a1));
        atomicAdd(&acc[a2 >> 20], expand_pkt(a2));
        atomicAdd(&acc[a3 >> 20], expand_pkt(a3));
    }
    for (unsigned i = (v1 << 2) + t; i < i1; i += ACC_THREADS) {
        unsigned r = rb[i];
        atomicAdd(&acc[r >> 20], expand_pkt(r));
    }
    __syncthreads();

    // dump (both slices race into same region; garbage sink, ≤ 8 MB)
    unsigned long long* pb = dump + (size_t)b * BKT_RANGE;
    #pragma unroll
    for (int k = 0; k < BKT_RANGE / ACC_THREADS; ++k)
        pb[k * ACC_THREADS + t] = acc[k * ACC_THREADS + t];
}

// ------------------------ ABLATION 2: gathers kept, no LDS atomics (y) -----
__global__ __launch_bounds__(ACC_THREADS) void tgnn_accum_y(
    const unsigned* __restrict__ qnf,
    const unsigned* __restrict__ rec,
    const unsigned* __restrict__ cursor,
    unsigned long long* __restrict__ dump)   // d_out sink, overwritten later
{
    int b = blockIdx.x >> 1;
    int s = blockIdx.x & 1;
    int t = threadIdx.x;

    unsigned count = cursor[b] - (unsigned)b * BKT_CAP;
    if (count > BKT_CAP) count = BKT_CAP;
    unsigned mid = (count >> 1) & ~3u;
    unsigned i0 = s ? mid : 0u;
    unsigned i1 = s ? count : mid;

    const unsigned* rb  = rec + (size_t)b * BKT_CAP;
    const int4*     rb4 = (const int4*)rb;

    unsigned v0 = i0 >> 2;
    unsigned v1 = i1 >> 2;
    unsigned v  = v0 + t;
    unsigned long long sink = 0;

    for (; v + ACC_THREADS < v1; v += 2 * ACC_THREADS) {
        int4 ra = rb4[v];
        int4 rc = rb4[v + ACC_THREADS];
        unsigned a0 = (unsigned)ra.x, a1 = (unsigned)ra.y;
        unsigned a2 = (unsigned)ra.z, a3 = (unsigned)ra.w;
        unsigned c0 = (unsigned)rc.x, c1 = (unsigned)rc.y;
        unsigned c2 = (unsigned)rc.z, c3 = (unsigned)rc.w;
        unsigned qa0 = gather_sc0(qnf + (a0 & 0xFFFFFu));
        unsigned qa1 = gather_sc0(qnf + (a1 & 0xFFFFFu));
        unsigned qa2 = gather_sc0(qnf + (a2 & 0xFFFFFu));
        unsigned qa3 = gather_sc0(qnf + (a3 & 0xFFFFFu));
        unsigned qc0 = gather_sc0(qnf + (c0 & 0xFFFFFu));
        unsigned qc1 = gather_sc0(qnf + (c1 & 0xFFFFFu));
        unsigned qc2 = gather_sc0(qnf + (c2 & 0xFFFFFu));
        unsigned qc3 = gather_sc0(qnf + (c3 & 0xFFFFFu));
        sink ^= expand_pkt(qa0) ^ expand_pkt(qa1) ^ expand_pkt(qa2) ^ expand_pkt(qa3);
        sink ^= expand_pkt(qc0) ^ expand_pkt(qc1) ^ expand_pkt(qc2) ^ expand_pkt(qc3);
    }
    for (; v < v1; v += ACC_THREADS) {
        int4 ra = rb4[v];
        unsigned a0 = (unsigned)ra.x, a1 = (unsigned)ra.y;
        unsigned a2 = (unsigned)ra.z, a3 = (unsigned)ra.w;
        sink ^= expand_pkt(gather_sc0(qnf + (a0 & 0xFFFFFu)));
        sink ^= expand_pkt(gather_sc0(qnf + (a1 & 0xFFFFFu)));
        sink ^= expand_pkt(gather_sc0(qnf + (a2 & 0xFFFFFu)));
        sink ^= expand_pkt(gather_sc0(qnf + (a3 & 0xFFFFFu)));
    }
    for (unsigned i = (v1 << 2) + t; i < i1; i += ACC_THREADS) {
        unsigned r = rb[i];
        sink ^= expand_pkt(gather_sc0(qnf + (r & 0xFFFFFu)));
    }
    // keep everything live; ≤ 4 MB into the 8 MB d_out sink
    dump[(size_t)blockIdx.x * ACC_THREADS + t] = sink;
}

// ---------------------------------------------------------- merge+node -----
__global__ __launch_bounds__(256) void tgnn_merge_node_kernel(
    const float2* __restrict__ nf,
    const unsigned long long* __restrict__ partial,
    const float* __restrict__ P,
    float2* __restrict__ out, int n_nodes)
{
    __shared__ float p[194];
    for (int k = threadIdx.x; k < 194; k += 256) p[k] = P[k];
    __syncthreads();

    int i = blockIdx.x * 256 + threadIdx.x;
    if (i >= n_nodes) return;

    unsigned long long v = partial[i] + partial[NODE_SPACE + i];
    unsigned c = (unsigned)(v >> 52);
    float a0, a1;
    if (c > 0) {
        float inv = 1.0f / (float)c;
        float X = (float)(unsigned)(v & 0x3FFFFFFull);
        float Y = (float)(unsigned)((v >> 26) & 0x3FFFFFFull);
        a0 = X * inv * (1.0f / 4096.0f) - 8.0f;
        a1 = Y * inv * (1.0f / 4096.0f) - 8.0f;
    } else {
        float2 f = nf[i];
        a0 = f.x;
        a1 = f.y;
    }

    float o0 = p[192], o1 = p[193];
    #pragma unroll
    for (int j = 0; j < 16; ++j) {
        float gr = fmaf(p[j],      a0, fmaf(p[48 + j], a1, p[96 + j]));
        float gz = fmaf(p[16 + j], a0, fmaf(p[64 + j], a1, p[112 + j]));
        float gn = fmaf(p[32 + j], a0, fmaf(p[80 + j], a1, p[128 + j]));
        float r  = 1.0f / (1.0f + __expf(-gr));
        float z  = 1.0f / (1.0f + __expf(-gz));
        float tt = fmaf(r, p[144 + j], gn);
        tt = fminf(fmaxf(tt, -12.0f), 12.0f);
        float e  = __expf(2.0f * tt);
        float n  = (e - 1.0f) / (e + 1.0f);
        float h  = (1.0f - z) * n;
        o0 = fmaf(p[160 + j], h, o0);
        o1 = fmaf(p[176 + j], h, o1);
    }
    out[i] = make_float2(o0, o1);
}

// ----------------------------------------------- fallback (R3 atomic path) --
__global__ __launch_bounds__(256) void tgnn_edge_kernel(
    const unsigned* __restrict__ qnf,
    const int* __restrict__ src,
    const int* __restrict__ dst,
    unsigned long long* __restrict__ pack,
    int n_edges)
{
    int tid    = blockIdx.x * blockDim.x + threadIdx.x;
    int stride = gridDim.x * blockDim.x;
    int n4     = n_edges >> 2;
    const int4* __restrict__ src4 = (const int4*)src;
    const int4* __restrict__ dst4 = (const int4*)dst;
    for (int i = tid; i < n4; i += stride) {
        int4 s = src4[i];
        int4 d = dst4[i];
        unsigned q0 = qnf[s.x], q1 = qnf[s.y], q2 = qnf[s.z], q3 = qnf[s.w];
        atomicAdd(&pack[d.x], expand_pkt(q0));
        atomicAdd(&pack[d.y], expand_pkt(q1));
        atomicAdd(&pack[d.z], expand_pkt(q2));
        atomicAdd(&pack[d.w], expand_pkt(q3));
    }
    for (int e = (n4 << 2) + tid; e < n_edges; e += stride)
        atomicAdd(&pack[dst[e]], expand_pkt(qnf[src[e]]));
}

__global__ __launch_bounds__(256) void tgnn_node_kernel(
    const float2* __restrict__ nf,
    const unsigned long long* __restrict__ pack,
    const float* __restrict__ P,
    float2* __restrict__ out, int n_nodes)
{
    __shared__ float p[194];
    for (int k = threadIdx.x; k < 194; k += 256) p[k] = P[k];
    __syncthreads();
    int i = blockIdx.x * 256 + threadIdx.x;
    if (i >= n_nodes) return;
    unsigned long long v = pack[i];
    unsigned c = (unsigned)(v >> 52);
    float a0, a1;
    if (c > 0) {
        float inv = 1.0f / (float)c;
        float X = (float)(unsigned)(v & 0x3FFFFFFull);
        float Y = (float)(unsigned)((v >> 26) & 0x3FFFFFFull);
        a0 = X * inv * (1.0f / 4096.0f) - 8.0f;
        a1 = Y * inv * (1.0f / 4096.0f) - 8.0f;
    } else {
        float2 f = nf[i];
        a0 = f.x; a1 = f.y;
    }
    float o0 = p[192], o1 = p[193];
    #pragma unroll
    for (int j = 0; j < 16; ++j) {
        float gr = fmaf(p[j],      a0, fmaf(p[48 + j], a1, p[96 + j]));
        float gz = fmaf(p[16 + j], a0, fmaf(p[64 + j], a1, p[112 + j]));
        float gn = fmaf(p[32 + j], a0, fmaf(p[80 + j], a1, p[128 + j]));
        float r  = 1.0f / (1.0f + __expf(-gr));
        float z  = 1.0f / (1.0f + __expf(-gz));
        float tt = fmaf(r, p[144 + j], gn);
        tt = fminf(fmaxf(tt, -12.0f), 12.0f);
        float e  = __expf(2.0f * tt);
        float n  = (e - 1.0f) / (e + 1.0f);
        float h  = (1.0f - z) * n;
        o0 = fmaf(p[160 + j], h, o0);
        o1 = fmaf(p[176 + j], h, o1);
    }
    out[i] = make_float2(o0, o1);
}

// -------------------------------------------------------------- launch -----
extern "C" void kernel_launch(void* const* d_in, const int* in_sizes, int n_in,
                              void* d_out, int out_size, void* d_ws, size_t ws_size,
                              hipStream_t stream)
{
    const float* nf    = (const float*)d_in[0];
    const int*   ei    = (const int*)d_in[1];
    const float* W_msg = (const float*)d_in[2];
    const float* b_msg = (const float*)d_in[3];
    const float* W_ih  = (const float*)d_in[4];
    const float* b_ih  = (const float*)d_in[6];
    const float* b_hh  = (const float*)d_in[7];
    const float* W_cls = (const float*)d_in[8];
    const float* b_cls = (const float*)d_in[9];
    float* out = (float*)d_out;

    const int N = in_sizes[0] / 2;
    const int E = in_sizes[1] / 2;
    const int qBlocks = (N + 255) / 256;

    size_t off = 0;
    auto take = [&](size_t bytes) { size_t o = off; off = (off + bytes + 255) & ~(size_t)255; return o; };
    size_t partialOff = take((size_t)SPLIT * NODE_SPACE * 8);
    size_t recOff     = take((size_t)NBKT * BKT_CAP * 4);
    size_t qnfOff     = take((size_t)N * 4);
    size_t curOff     = take((size_t)NBKT * 4);
    size_t pOff       = take(194 * 4);
    size_t need = off;

    char* ws = (char*)d_ws;

    if (ws_size >= need) {
        unsigned long long* partial = (unsigned long long*)(ws + partialOff);
        unsigned* rec    = (unsigned*)(ws + recOff);
        unsigned* qnf    = (unsigned*)(ws + qnfOff);
        unsigned* cursor = (unsigned*)(ws + curOff);
        float*    P      = (float*)(ws + pOff);

        (void)hipMemsetAsync(partial, 0, (size_t)NODE_SPACE * 8, stream);

        tgnn_cursor_init<<<1, 256, 0, stream>>>(cursor);
        tgnn_prep_kernel<<<1, 64, 0, stream>>>(W_msg, b_msg, W_ih, b_ih, b_hh,
                                               W_cls, b_cls, P);
        tgnn_quant_kernel<<<qBlocks, 256, 0, stream>>>((const float2*)nf, qnf, N);

        int binBlocks = (E + CHUNK - 1) / CHUNK;
        tgnn_bin_kernel<<<binBlocks, BIN_THREADS, 0, stream>>>(ei, ei + E, qnf, rec,
                                                               cursor, partial, E);

        tgnn_accum_kernel<<<NBKT * SPLIT, ACC_THREADS, 0, stream>>>(qnf, rec,
                                                                    cursor, partial);

        // ---- ablations (full workload, dump into d_out; merge overwrites) --
        tgnn_accum_ng<<<NBKT * SPLIT, ACC_THREADS, 0, stream>>>(rec, cursor,
                                                    (unsigned long long*)d_out);
        tgnn_accum_y<<<NBKT * SPLIT, ACC_THREADS, 0, stream>>>(qnf, rec, cursor,
                                                    (unsigned long long*)d_out);

        tgnn_merge_node_kernel<<<qBlocks, 256, 0, stream>>>((const float2*)nf, partial,
                                                            P, (float2*)out, N);
    } else {
        unsigned long long* pack = (unsigned long long*)ws;
        unsigned* qnf = (unsigned*)(ws + (size_t)N * 8);
        float*    P   = (float*)(ws + (size_t)N * 12);

        (void)hipMemsetAsync(pack, 0, (size_t)N * 8, stream);
        tgnn_prep_kernel<<<1, 64, 0, stream>>>(W_msg, b_msg, W_ih, b_ih, b_hh,
                                               W_cls, b_cls, P);
        tgnn_quant_kernel<<<qBlocks, 256, 0, stream>>>((const float2*)nf, qnf, N);
        tgnn_edge_kernel<<<2048, 256, 0, stream>>>(qnf, ei, ei + E, pack, E);
        tgnn_node_kernel<<<qBlocks, 256, 0, stream>>>((const float2*)nf, pack,
                                                      P, (float2*)out, N);
    }
}

// Round 10
// 333.974 us; speedup vs baseline: 1.5299x; 1.5299x over previous
//
#include <hip/hip_runtime.h>

// ---------------------------------------------------------------------------
// AML_TGNN: segment-mean over edges -> folded (msg-linear + GRU(h0=0)) -> cls
//
// R10 = payload-carrying records. R9 ablation: accum's gather (~75us) and
// LDS-atomic+stream (~105us) are ADDITIVE (ng+y = 177 ~= control 180) -- no
// overlap possible inside accum (atomic depends on own gather, nothing else
// to issue). Fix: carry the (10-bit) quantized payload IN the record, so the
// random gather moves into bin where it issues at edge-load time and hides
// under the hist/scan/claim LDS machinery; accum becomes gather-free.
//
//   qnf10[i] u32 = qx | qy<<10            (q = round((v+8)*64), 10 bits each)
//   record  u32 = q20 << 12 | dstLow12
//   packet  u64 = (1<<52) | (qy<<26) | qx  (sums < 2^26 for cnt <= 4095) 
//   decode: a = (X / cnt) / 64 - 8
//
// Pipeline: memset(partial0) -> prep(+cursor) -> quant -> bin -> accum
//           -> merge_node. Fallback: R3 one-atomic-per-edge if ws small.
// Precision: step 1/64 -> worst mean error ~0.004/component, output gain
// ~0.5-1.5 -> ~0.008 + 0.0039 bf16 floor << 0.0196 threshold.
// ---------------------------------------------------------------------------

#define NBKT        256
#define BKT_SHIFT   12
#define DLOW_MASK   4095u
#define BKT_CAP     139264u
#define CHUNK       16384
#define BIN_THREADS 512
#define ACC_THREADS 1024
#define SPLIT       2
#define BKT_RANGE   4096
#define NODE_SPACE  (NBKT * BKT_RANGE)

// expand 20-bit payload (qx10 | qy10<<10) into the u64 accumulate packet
__device__ __forceinline__ unsigned long long expand_pkt(unsigned p20)
{
    return (1ull << 52) | ((unsigned long long)(p20 >> 10) << 26)
                        | (unsigned long long)(p20 & 1023u);
}

__device__ __forceinline__ unsigned gather_sc0(const unsigned* p)
{
    return __hip_atomic_load(p, __ATOMIC_RELAXED, __HIP_MEMORY_SCOPE_AGENT);
}

// ------------------------------------------------------- prep (+cursor) ----
__global__ __launch_bounds__(256) void tgnn_prep_kernel(
    const float* __restrict__ W_msg, const float* __restrict__ b_msg,
    const float* __restrict__ W_ih,  const float* __restrict__ b_ih,
    const float* __restrict__ b_hh,  const float* __restrict__ W_cls,
    const float* __restrict__ b_cls, float* __restrict__ P,
    unsigned* __restrict__ cursor)
{
    int j = threadIdx.x;
    cursor[j] = (unsigned)j * BKT_CAP;          // all 256 buckets
    if (j < 48) {
        float a0 = 0.f, a1 = 0.f, dd = 0.f;
        #pragma unroll
        for (int k = 0; k < 16; ++k) {
            float w = W_ih[j * 16 + k];
            a0 += w * W_msg[k * 2 + 0];
            a1 += w * W_msg[k * 2 + 1];
            dd += w * b_msg[k];
        }
        dd += b_ih[j];
        P[j]      = a0;
        P[48 + j] = a1;
        if (j < 16)      P[96 + j]         = dd + b_hh[j];
        else if (j < 32) P[112 + (j - 16)] = dd + b_hh[j];
        else             P[128 + (j - 32)] = dd;
    }
    if (j < 16) {
        P[144 + j] = b_hh[32 + j];
        P[160 + j] = W_cls[j];
        P[176 + j] = W_cls[16 + j];
    }
    if (j == 0) { P[192] = b_cls[0]; P[193] = b_cls[1]; }
}

// --------------------------------------------------------- quant (10-bit) --
__global__ __launch_bounds__(256) void tgnn_quant_kernel(
    const float2* __restrict__ nf, unsigned* __restrict__ qnf, int n)
{
    int i = blockIdx.x * blockDim.x + threadIdx.x;
    if (i >= n) return;
    float2 f = nf[i];
    float x = fminf(fmaxf(f.x, -7.9f), 7.9f);
    float y = fminf(fmaxf(f.y, -7.9f), 7.9f);
    unsigned qx = (unsigned)fmaf(x, 64.0f, 512.5f);   // round((x+8)*64)
    unsigned qy = (unsigned)fmaf(y, 64.0f, 512.5f);
    qnf[i] = qx | (qy << 10);                          // 20 bits
}

// ----------------------------------------------------------------- bin -----
__global__ __launch_bounds__(BIN_THREADS) void tgnn_bin_kernel(
    const int* __restrict__ src, const int* __restrict__ dst,
    const unsigned* __restrict__ qnf,
    unsigned* __restrict__ rec, unsigned* __restrict__ cursor,
    unsigned long long* __restrict__ partial0,
    int n_edges)
{
    __shared__ unsigned cnt[NBKT];
    __shared__ unsigned pos[NBKT];
    __shared__ unsigned scur[NBKT];
    __shared__ unsigned gbase[NBKT];
    __shared__ unsigned stage[CHUNK];   // 64 KB

    int t  = threadIdx.x;
    int e0 = blockIdx.x * CHUNK;
    int ne = n_edges - e0;
    if (ne <= 0) return;
    if (ne > CHUNK) ne = CHUNK;
    int nv4 = (ne + 3) >> 2;

    const int4* s4p = (const int4*)(src + e0);
    const int4* d4p = (const int4*)(dst + e0);

    // load edges and ISSUE ALL 32 PAYLOAD GATHERS immediately; results are
    // first needed in the stage phase, so they hide under histogram+scan.
    int4 dr[8];
    unsigned q[32];
    #pragma unroll
    for (int j = 0; j < 8; ++j) {
        int i4 = j * BIN_THREADS + t;
        if (i4 < nv4) {
            dr[j] = d4p[i4];
            int4 s = s4p[i4];
            q[4 * j + 0] = gather_sc0(qnf + (unsigned)s.x);
            q[4 * j + 1] = gather_sc0(qnf + (unsigned)s.y);
            q[4 * j + 2] = gather_sc0(qnf + (unsigned)s.z);
            q[4 * j + 3] = gather_sc0(qnf + (unsigned)s.w);
        } else {
            dr[j] = make_int4(0, 0, 0, 0);
            q[4 * j + 0] = q[4 * j + 1] = q[4 * j + 2] = q[4 * j + 3] = 0;
        }
    }

    if (t < NBKT) cnt[t] = 0;
    __syncthreads();

    // histogram (dst only)
    #pragma unroll
    for (int j = 0; j < 8; ++j) {
        int base = 4 * (j * BIN_THREADS + t);
        if (base < ne) {
            int lim = ne - base;
            int dv[4] = { dr[j].x, dr[j].y, dr[j].z, dr[j].w };
            #pragma unroll
            for (int c = 0; c < 4; ++c)
                if (c < lim) atomicAdd(&cnt[((unsigned)dv[c]) >> BKT_SHIFT], 1u);
        }
    }
    __syncthreads();

    // exclusive scan over 256 buckets
    if (t < NBKT) pos[t] = cnt[t];
    __syncthreads();
    #pragma unroll
    for (int off = 1; off < NBKT; off <<= 1) {
        unsigned v = 0, a = 0;
        if (t < NBKT) { v = pos[t]; a = (t >= off) ? pos[t - off] : 0u; }
        __syncthreads();
        if (t < NBKT) pos[t] = v + a;
        __syncthreads();
    }
    if (t < NBKT) {
        unsigned myCnt  = cnt[t];
        unsigned myBase = pos[t] - myCnt;
        scur[t] = myBase;
        pos[t]  = myBase;
        gbase[t] = myCnt ? atomicAdd(&cursor[t], myCnt) : 0u;
    }
    __syncthreads();

    // stage records (payload<<12 | dstLow) bucket-grouped in LDS
    #pragma unroll
    for (int j = 0; j < 8; ++j) {
        int base = 4 * (j * BIN_THREADS + t);
        if (base < ne) {
            int lim = ne - base;
            int dv[4] = { dr[j].x, dr[j].y, dr[j].z, dr[j].w };
            #pragma unroll
            for (int c = 0; c < 4; ++c) if (c < lim) {
                unsigned d = (unsigned)dv[c];
                unsigned b = d >> BKT_SHIFT;
                unsigned p = atomicAdd(&scur[b], 1u);
                stage[p] = (q[4 * j + c] << 12) | (d & DLOW_MASK);
            }
        }
    }
    __syncthreads();

    // coalesced flush; overflow -> direct u64 atomic into partial0
    int wave = t >> 6, lane = t & 63;
    for (int b = wave; b < NBKT; b += BIN_THREADS / 64) {
        unsigned n = cnt[b];
        if (!n) continue;
        unsigned sb = pos[b];
        unsigned gb = gbase[b];
        unsigned capEnd = (unsigned)(b + 1) * BKT_CAP;
        for (unsigned i = lane; i < n; i += 64) {
            unsigned r = stage[sb + i];
            unsigned slot = gb + i;
            if (slot < capEnd) {
                rec[slot] = r;
            } else {    // statistically never; correctness guarantee only
                unsigned node = ((unsigned)b << BKT_SHIFT) | (r & DLOW_MASK);
                atomicAdd(&partial0[node], expand_pkt(r >> 12));
            }
        }
    }
}

// --------------------------------------------------- accum (gather-free) ---
__global__ __launch_bounds__(ACC_THREADS) void tgnn_accum_kernel(
    const unsigned* __restrict__ rec,
    const unsigned* __restrict__ cursor,
    unsigned long long* __restrict__ partial)
{
    __shared__ unsigned long long acc[BKT_RANGE];
    int b = blockIdx.x >> 1;            // SPLIT = 2
    int s = blockIdx.x & 1;
    int t = threadIdx.x;

    unsigned count = cursor[b] - (unsigned)b * BKT_CAP;
    if (count > BKT_CAP) count = BKT_CAP;           // overflow went direct
    unsigned mid = (count >> 1) & ~3u;
    unsigned i0 = s ? mid : 0u;
    unsigned i1 = s ? count : mid;

    unsigned long long* pb = partial + (size_t)s * NODE_SPACE + (size_t)b * BKT_RANGE;
    if (s == 0) {
        // seed from partial0 (overflow contributions; usually all zero)
        #pragma unroll
        for (int k = 0; k < BKT_RANGE / ACC_THREADS; ++k)
            acc[k * ACC_THREADS + t] = pb[k * ACC_THREADS + t];
    } else {
        #pragma unroll
        for (int k = 0; k < BKT_RANGE / ACC_THREADS; ++k)
            acc[k * ACC_THREADS + t] = 0ull;
    }
    __syncthreads();

    const unsigned* rb  = rec + (size_t)b * BKT_CAP;
    const int4*     rb4 = (const int4*)rb;

    unsigned v0 = i0 >> 2;
    unsigned v1 = i1 >> 2;
    for (unsigned v = v0 + t; v < v1; v += ACC_THREADS) {
        int4 ra = rb4[v];
        unsigned r0 = (unsigned)ra.x, r1 = (unsigned)ra.y;
        unsigned r2 = (unsigned)ra.z, r3 = (unsigned)ra.w;
        atomicAdd(&acc[r0 & DLOW_MASK], expand_pkt(r0 >> 12));
        atomicAdd(&acc[r1 & DLOW_MASK], expand_pkt(r1 >> 12));
        atomicAdd(&acc[r2 & DLOW_MASK], expand_pkt(r2 >> 12));
        atomicAdd(&acc[r3 & DLOW_MASK], expand_pkt(r3 >> 12));
    }
    for (unsigned i = (v1 << 2) + t; i < i1; i += ACC_THREADS) {
        unsigned r = rb[i];
        atomicAdd(&acc[r & DLOW_MASK], expand_pkt(r >> 12));
    }
    __syncthreads();

    #pragma unroll
    for (int k = 0; k < BKT_RANGE / ACC_THREADS; ++k)
        pb[k * ACC_THREADS + t] = acc[k * ACC_THREADS + t];
}

// ---------------------------------------------------------- merge+node -----
__global__ __launch_bounds__(256) void tgnn_merge_node_kernel(
    const float2* __restrict__ nf,
    const unsigned long long* __restrict__ partial,
    const float* __restrict__ P,
    float2* __restrict__ out, int n_nodes)
{
    __shared__ float p[194];
    for (int k = threadIdx.x; k < 194; k += 256) p[k] = P[k];
    __syncthreads();

    int i = blockIdx.x * 256 + threadIdx.x;
    if (i >= n_nodes) return;

    unsigned long long v = partial[i] + partial[NODE_SPACE + i];
    unsigned c = (unsigned)(v >> 52);
    float a0, a1;
    if (c > 0) {
        float inv = 1.0f / (float)c;
        float X = (float)(unsigned)(v & 0x3FFFFFFull);
        float Y = (float)(unsigned)((v >> 26) & 0x3FFFFFFull);
        a0 = X * inv * (1.0f / 64.0f) - 8.0f;
        a1 = Y * inv * (1.0f / 64.0f) - 8.0f;
    } else {
        float2 f = nf[i];
        a0 = f.x;
        a1 = f.y;
    }

    float o0 = p[192], o1 = p[193];
    #pragma unroll
    for (int j = 0; j < 16; ++j) {
        float gr = fmaf(p[j],      a0, fmaf(p[48 + j], a1, p[96 + j]));
        float gz = fmaf(p[16 + j], a0, fmaf(p[64 + j], a1, p[112 + j]));
        float gn = fmaf(p[32 + j], a0, fmaf(p[80 + j], a1, p[128 + j]));
        float r  = 1.0f / (1.0f + __expf(-gr));
        float z  = 1.0f / (1.0f + __expf(-gz));
        float tt = fmaf(r, p[144 + j], gn);
        tt = fminf(fmaxf(tt, -12.0f), 12.0f);
        float e  = __expf(2.0f * tt);
        float n  = (e - 1.0f) / (e + 1.0f);
        float h  = (1.0f - z) * n;
        o0 = fmaf(p[160 + j], h, o0);
        o1 = fmaf(p[176 + j], h, o1);
    }
    out[i] = make_float2(o0, o1);
}

// ----------------------------------------------- fallback (R3 atomic path) --
__global__ __launch_bounds__(256) void tgnn_edge_kernel(
    const unsigned* __restrict__ qnf,
    const int* __restrict__ src,
    const int* __restrict__ dst,
    unsigned long long* __restrict__ pack,
    int n_edges)
{
    int tid    = blockIdx.x * blockDim.x + threadIdx.x;
    int stride = gridDim.x * blockDim.x;
    int n4     = n_edges >> 2;
    const int4* __restrict__ src4 = (const int4*)src;
    const int4* __restrict__ dst4 = (const int4*)dst;
    for (int i = tid; i < n4; i += stride) {
        int4 s = src4[i];
        int4 d = dst4[i];
        unsigned q0 = qnf[s.x], q1 = qnf[s.y], q2 = qnf[s.z], q3 = qnf[s.w];
        atomicAdd(&pack[d.x], expand_pkt(q0));
        atomicAdd(&pack[d.y], expand_pkt(q1));
        atomicAdd(&pack[d.z], expand_pkt(q2));
        atomicAdd(&pack[d.w], expand_pkt(q3));
    }
    for (int e = (n4 << 2) + tid; e < n_edges; e += stride)
        atomicAdd(&pack[dst[e]], expand_pkt(qnf[src[e]]));
}

__global__ __launch_bounds__(256) void tgnn_node_kernel(
    const float2* __restrict__ nf,
    const unsigned long long* __restrict__ pack,
    const float* __restrict__ P,
    float2* __restrict__ out, int n_nodes)
{
    __shared__ float p[194];
    for (int k = threadIdx.x; k < 194; k += 256) p[k] = P[k];
    __syncthreads();
    int i = blockIdx.x * 256 + threadIdx.x;
    if (i >= n_nodes) return;
    unsigned long long v = pack[i];
    unsigned c = (unsigned)(v >> 52);
    float a0, a1;
    if (c > 0) {
        float inv = 1.0f / (float)c;
        float X = (float)(unsigned)(v & 0x3FFFFFFull);
        float Y = (float)(unsigned)((v >> 26) & 0x3FFFFFFull);
        a0 = X * inv * (1.0f / 64.0f) - 8.0f;
        a1 = Y * inv * (1.0f / 64.0f) - 8.0f;
    } else {
        float2 f = nf[i];
        a0 = f.x; a1 = f.y;
    }
    float o0 = p[192], o1 = p[193];
    #pragma unroll
    for (int j = 0; j < 16; ++j) {
        float gr = fmaf(p[j],      a0, fmaf(p[48 + j], a1, p[96 + j]));
        float gz = fmaf(p[16 + j], a0, fmaf(p[64 + j], a1, p[112 + j]));
        float gn = fmaf(p[32 + j], a0, fmaf(p[80 + j], a1, p[128 + j]));
        float r  = 1.0f / (1.0f + __expf(-gr));
        float z  = 1.0f / (1.0f + __expf(-gz));
        float tt = fmaf(r, p[144 + j], gn);
        tt = fminf(fmaxf(tt, -12.0f), 12.0f);
        float e  = __expf(2.0f * tt);
        float n  = (e - 1.0f) / (e + 1.0f);
        float h  = (1.0f - z) * n;
        o0 = fmaf(p[160 + j], h, o0);
        o1 = fmaf(p[176 + j], h, o1);
    }
    out[i] = make_float2(o0, o1);
}

// -------------------------------------------------------------- launch -----
extern "C" void kernel_launch(void* const* d_in, const int* in_sizes, int n_in,
                              void* d_out, int out_size, void* d_ws, size_t ws_size,
                              hipStream_t stream)
{
    const float* nf    = (const float*)d_in[0];
    const int*   ei    = (const int*)d_in[1];
    const float* W_msg = (const float*)d_in[2];
    const float* b_msg = (const float*)d_in[3];
    const float* W_ih  = (const float*)d_in[4];
    const float* b_ih  = (const float*)d_in[6];
    const float* b_hh  = (const float*)d_in[7];
    const float* W_cls = (const float*)d_in[8];
    const float* b_cls = (const float*)d_in[9];
    float* out = (float*)d_out;

    const int N = in_sizes[0] / 2;
    const int E = in_sizes[1] / 2;
    const int qBlocks = (N + 255) / 256;

    size_t off = 0;
    auto take = [&](size_t bytes) { size_t o = off; off = (off + bytes + 255) & ~(size_t)255; return o; };
    size_t partialOff = take((size_t)SPLIT * NODE_SPACE * 8);
    size_t recOff     = take((size_t)NBKT * BKT_CAP * 4);
    size_t qnfOff     = take((size_t)N * 4);
    size_t curOff     = take((size_t)NBKT * 4);
    size_t pOff       = take(194 * 4);
    size_t need = off;

    char* ws = (char*)d_ws;

    if (ws_size >= need) {
        unsigned long long* partial = (unsigned long long*)(ws + partialOff);
        unsigned* rec    = (unsigned*)(ws + recOff);
        unsigned* qnf    = (unsigned*)(ws + qnfOff);
        unsigned* cursor = (unsigned*)(ws + curOff);
        float*    P      = (float*)(ws + pOff);

        (void)hipMemsetAsync(partial, 0, (size_t)NODE_SPACE * 8, stream);

        tgnn_prep_kernel<<<1, 256, 0, stream>>>(W_msg, b_msg, W_ih, b_ih, b_hh,
                                                W_cls, b_cls, P, cursor);
        tgnn_quant_kernel<<<qBlocks, 256, 0, stream>>>((const float2*)nf, qnf, N);

        int binBlocks = (E + CHUNK - 1) / CHUNK;
        tgnn_bin_kernel<<<binBlocks, BIN_THREADS, 0, stream>>>(ei, ei + E, qnf, rec,
                                                               cursor, partial, E);

        tgnn_accum_kernel<<<NBKT * SPLIT, ACC_THREADS, 0, stream>>>(rec, cursor,
                                                                    partial);

        tgnn_merge_node_kernel<<<qBlocks, 256, 0, stream>>>((const float2*)nf, partial,
                                                            P, (float2*)out, N);
    } else {
        unsigned long long* pack = (unsigned long long*)ws;
        unsigned* qnf = (unsigned*)(ws + (size_t)N * 8);
        float*    P   = (float*)(ws + (size_t)N * 12);
        unsigned* cursorDummy = (unsigned*)(ws + (size_t)N * 12 + 1024);

        (void)hipMemsetAsync(pack, 0, (size_t)N * 8, stream);
        tgnn_prep_kernel<<<1, 256, 0, stream>>>(W_msg, b_msg, W_ih, b_ih, b_hh,
                                                W_cls, b_cls, P, cursorDummy);
        tgnn_quant_kernel<<<qBlocks, 256, 0, stream>>>((const float2*)nf, qnf, N);
        tgnn_edge_kernel<<<2048, 256, 0, stream>>>(qnf, ei, ei + E, pack, E);
        tgnn_node_kernel<<<qBlocks, 256, 0, stream>>>((const float2*)nf, pack,
                                                      P, (float2*)out, N);
    }
}

// Round 11
// 325.172 us; speedup vs baseline: 1.5713x; 1.0271x over previous
//
#include <hip/hip_runtime.h>

// ---------------------------------------------------------------------------
// AML_TGNN: segment-mean over edges -> folded (msg-linear + GRU(h0=0)) -> cls
//
// R11 = 3-pass radix, gather made COALESCED. Evidence: R10 showed the 32M
// divergent qnf gathers cost ~145-185us wherever placed (request-rate wall),
// while gather-free accum (stream+LDS atomics) is <30us. So eliminate the
// divergent gather entirely:
//   bin1 : bin edges by src>>12; record = dst20<<12 | srcLow12 (no gather)
//   pass2: per (src-bucket, slice): qnf slice (16KB) -> LDS coalesced;
//          payload = LDS lookup; re-bin by dst>>12; record = q20<<12 | dstLow
//   accum: gather-free accumulate per dst-bucket (R10 version)
// ws ~1GB (R8 trace: poison fill = 1.024e9 B) -> rec1+rec2 (2x142.6MB) fit.
//
// quant: q = round((v+8)*64) 10-bit/comp, qnf = qx | qy<<10 (20 bits)
// packet u64 = (1<<52) | (qy<<26) | qx ; decode a = (X/cnt)/64 - 8
// Overflow (statistically never): direct u64 atomic into partial slice 0.
// ---------------------------------------------------------------------------

#define NBKT        256
#define BKT_SHIFT   12
#define DLOW_MASK   4095u
#define BKT_CAP     139264u         // mu=131072 (244 active buckets) + 22.6s
#define CHUNK       16384
#define BIN_THREADS 512
#define CHUNK2      8192
#define SLICES2     ((BKT_CAP + CHUNK2 - 1) / CHUNK2)   // 17
#define ACC_THREADS 1024
#define SPLIT       2
#define BKT_RANGE   4096
#define NODE_SPACE  (NBKT * BKT_RANGE)

// expand 20-bit payload (qx10 | qy10<<10) into the u64 accumulate packet
__device__ __forceinline__ unsigned long long expand_pkt(unsigned p20)
{
    return (1ull << 52) | ((unsigned long long)(p20 >> 10) << 26)
                        | (unsigned long long)(p20 & 1023u);
}

// ------------------------------------------------------ prep (+cursors) ----
__global__ __launch_bounds__(256) void tgnn_prep_kernel(
    const float* __restrict__ W_msg, const float* __restrict__ b_msg,
    const float* __restrict__ W_ih,  const float* __restrict__ b_ih,
    const float* __restrict__ b_hh,  const float* __restrict__ W_cls,
    const float* __restrict__ b_cls, float* __restrict__ P,
    unsigned* __restrict__ cursor1, unsigned* __restrict__ cursor2)
{
    int j = threadIdx.x;
    cursor1[j] = (unsigned)j * BKT_CAP;
    cursor2[j] = (unsigned)j * BKT_CAP;
    if (j < 48) {
        float a0 = 0.f, a1 = 0.f, dd = 0.f;
        #pragma unroll
        for (int k = 0; k < 16; ++k) {
            float w = W_ih[j * 16 + k];
            a0 += w * W_msg[k * 2 + 0];
            a1 += w * W_msg[k * 2 + 1];
            dd += w * b_msg[k];
        }
        dd += b_ih[j];
        P[j]      = a0;
        P[48 + j] = a1;
        if (j < 16)      P[96 + j]         = dd + b_hh[j];
        else if (j < 32) P[112 + (j - 16)] = dd + b_hh[j];
        else             P[128 + (j - 32)] = dd;
    }
    if (j < 16) {
        P[144 + j] = b_hh[32 + j];
        P[160 + j] = W_cls[j];
        P[176 + j] = W_cls[16 + j];
    }
    if (j == 0) { P[192] = b_cls[0]; P[193] = b_cls[1]; }
}

// --------------------------------------------------------- quant (10-bit) --
__global__ __launch_bounds__(256) void tgnn_quant_kernel(
    const float2* __restrict__ nf, unsigned* __restrict__ qnf, int n)
{
    int i = blockIdx.x * blockDim.x + threadIdx.x;
    if (i >= n) return;
    float2 f = nf[i];
    float x = fminf(fmaxf(f.x, -7.9f), 7.9f);
    float y = fminf(fmaxf(f.y, -7.9f), 7.9f);
    unsigned qx = (unsigned)fmaf(x, 64.0f, 512.5f);   // round((x+8)*64)
    unsigned qy = (unsigned)fmaf(y, 64.0f, 512.5f);
    qnf[i] = qx | (qy << 10);                          // 20 bits
}

// ------------------------------------------------- bin1: bin by src>>12 ----
__global__ __launch_bounds__(BIN_THREADS) void tgnn_bin1_kernel(
    const int* __restrict__ src, const int* __restrict__ dst,
    const unsigned* __restrict__ qnf,
    unsigned* __restrict__ rec1, unsigned* __restrict__ cursor1,
    unsigned long long* __restrict__ partial0,
    int n_edges)
{
    __shared__ unsigned cnt[NBKT];
    __shared__ unsigned pos[NBKT];
    __shared__ unsigned scur[NBKT];
    __shared__ unsigned gbase[NBKT];
    __shared__ unsigned stage[CHUNK];   // 64 KB

    int t  = threadIdx.x;
    int e0 = blockIdx.x * CHUNK;
    int ne = n_edges - e0;
    if (ne <= 0) return;
    if (ne > CHUNK) ne = CHUNK;
    int nv4 = (ne + 3) >> 2;

    const int4* s4p = (const int4*)(src + e0);
    const int4* d4p = (const int4*)(dst + e0);

    int4 dr[8], sr[8];
    #pragma unroll
    for (int j = 0; j < 8; ++j) {
        int i4 = j * BIN_THREADS + t;
        if (i4 < nv4) { dr[j] = d4p[i4]; sr[j] = s4p[i4]; }
        else { dr[j] = make_int4(0,0,0,0); sr[j] = make_int4(0,0,0,0); }
    }

    if (t < NBKT) cnt[t] = 0;
    __syncthreads();

    // histogram over SRC bucket
    #pragma unroll
    for (int j = 0; j < 8; ++j) {
        int base = 4 * (j * BIN_THREADS + t);
        if (base < ne) {
            int lim = ne - base;
            int sv[4] = { sr[j].x, sr[j].y, sr[j].z, sr[j].w };
            #pragma unroll
            for (int c = 0; c < 4; ++c)
                if (c < lim) atomicAdd(&cnt[((unsigned)sv[c]) >> BKT_SHIFT], 1u);
        }
    }
    __syncthreads();

    if (t < NBKT) pos[t] = cnt[t];
    __syncthreads();
    #pragma unroll
    for (int off = 1; off < NBKT; off <<= 1) {
        unsigned v = 0, a = 0;
        if (t < NBKT) { v = pos[t]; a = (t >= off) ? pos[t - off] : 0u; }
        __syncthreads();
        if (t < NBKT) pos[t] = v + a;
        __syncthreads();
    }
    if (t < NBKT) {
        unsigned myCnt  = cnt[t];
        unsigned myBase = pos[t] - myCnt;
        scur[t] = myBase;
        pos[t]  = myBase;
        gbase[t] = myCnt ? atomicAdd(&cursor1[t], myCnt) : 0u;
    }
    __syncthreads();

    // stage records (dst20<<12 | srcLow12) grouped by src-bucket
    #pragma unroll
    for (int j = 0; j < 8; ++j) {
        int base = 4 * (j * BIN_THREADS + t);
        if (base < ne) {
            int lim = ne - base;
            int sv[4] = { sr[j].x, sr[j].y, sr[j].z, sr[j].w };
            int dv[4] = { dr[j].x, dr[j].y, dr[j].z, dr[j].w };
            #pragma unroll
            for (int c = 0; c < 4; ++c) if (c < lim) {
                unsigned s = (unsigned)sv[c];
                unsigned b = s >> BKT_SHIFT;
                unsigned p = atomicAdd(&scur[b], 1u);
                stage[p] = ((unsigned)dv[c] << 12) | (s & DLOW_MASK);
            }
        }
    }
    __syncthreads();

    // coalesced flush; overflow -> direct u64 atomic (one-off random gather)
    int wave = t >> 6, lane = t & 63;
    for (int b = wave; b < NBKT; b += BIN_THREADS / 64) {
        unsigned n = cnt[b];
        if (!n) continue;
        unsigned sb = pos[b];
        unsigned gb = gbase[b];
        unsigned capEnd = (unsigned)(b + 1) * BKT_CAP;
        for (unsigned i = lane; i < n; i += 64) {
            unsigned r = stage[sb + i];
            unsigned slot = gb + i;
            if (slot < capEnd) {
                rec1[slot] = r;
            } else {    // statistically never
                unsigned node = r >> 12;                       // dst
                unsigned s    = ((unsigned)b << BKT_SHIFT) | (r & DLOW_MASK);
                atomicAdd(&partial0[node], expand_pkt(qnf[s]));
            }
        }
    }
}

// ---------------- pass2: attach payload from LDS, re-bin by dst>>12 --------
__global__ __launch_bounds__(256) void tgnn_pass2_kernel(
    const unsigned* __restrict__ rec1, const unsigned* __restrict__ cursor1,
    const unsigned* __restrict__ qnf,
    unsigned* __restrict__ rec2, unsigned* __restrict__ cursor2,
    unsigned long long* __restrict__ partial0)
{
    __shared__ unsigned qlds[BKT_RANGE];   // 16 KB: this src-bucket's features
    __shared__ unsigned cnt[NBKT];
    __shared__ unsigned pos[NBKT];
    __shared__ unsigned scur[NBKT];
    __shared__ unsigned gbase[NBKT];
    __shared__ unsigned stage[CHUNK2];     // 32 KB

    int b = blockIdx.y;                    // src bucket
    int t = threadIdx.x;                   // 256 threads

    unsigned count = cursor1[b] - (unsigned)b * BKT_CAP;
    if (count > BKT_CAP) count = BKT_CAP;
    unsigned i0 = (unsigned)blockIdx.x * CHUNK2;
    if (i0 >= count) return;               // uniform across block
    unsigned ne = count - i0;
    if (ne > CHUNK2) ne = CHUNK2;
    int nv4 = (int)((ne + 3) >> 2);

    // coalesced load of the bucket's qnf slice
    const unsigned* qsrc = qnf + (size_t)b * BKT_RANGE;
    #pragma unroll
    for (int k = 0; k < BKT_RANGE / 256; ++k)
        qlds[k * 256 + t] = qsrc[k * 256 + t];

    const int4* r4p = (const int4*)(rec1 + (size_t)b * BKT_CAP + i0);
    int4 rr[8];
    #pragma unroll
    for (int j = 0; j < 8; ++j) {
        int i4 = j * 256 + t;
        rr[j] = (i4 < nv4) ? r4p[i4] : make_int4(0, 0, 0, 0);
    }

    cnt[t] = 0;
    __syncthreads();

    // histogram over DST bucket (record>>24)
    #pragma unroll
    for (int j = 0; j < 8; ++j) {
        int base = 4 * (j * 256 + t);
        if (base < (int)ne) {
            int lim = (int)ne - base;
            unsigned rv[4] = { (unsigned)rr[j].x, (unsigned)rr[j].y,
                               (unsigned)rr[j].z, (unsigned)rr[j].w };
            #pragma unroll
            for (int c = 0; c < 4; ++c)
                if (c < lim) atomicAdd(&cnt[rv[c] >> 24], 1u);
        }
    }
    __syncthreads();

    pos[t] = cnt[t];
    __syncthreads();
    #pragma unroll
    for (int off = 1; off < NBKT; off <<= 1) {
        unsigned v = pos[t];
        unsigned a = (t >= off) ? pos[t - off] : 0u;
        __syncthreads();
        pos[t] = v + a;
        __syncthreads();
    }
    {
        unsigned myCnt  = cnt[t];
        unsigned myBase = pos[t] - myCnt;
        scur[t] = myBase;
        pos[t]  = myBase;
        gbase[t] = myCnt ? atomicAdd(&cursor2[t], myCnt) : 0u;
    }
    __syncthreads();

    // stage payload-carrying records (q20<<12 | dstLow12) grouped by dst bkt
    #pragma unroll
    for (int j = 0; j < 8; ++j) {
        int base = 4 * (j * 256 + t);
        if (base < (int)ne) {
            int lim = (int)ne - base;
            unsigned rv[4] = { (unsigned)rr[j].x, (unsigned)rr[j].y,
                               (unsigned)rr[j].z, (unsigned)rr[j].w };
            #pragma unroll
            for (int c = 0; c < 4; ++c) if (c < lim) {
                unsigned r  = rv[c];
                unsigned bb = r >> 24;
                unsigned p  = atomicAdd(&scur[bb], 1u);
                stage[p] = (qlds[r & DLOW_MASK] << 12) | ((r >> 12) & DLOW_MASK);
            }
        }
    }
    __syncthreads();

    // coalesced flush to rec2; overflow -> direct u64 atomic into partial0
    int wave = t >> 6, lane = t & 63;
    for (int bb = wave; bb < NBKT; bb += 4) {
        unsigned n = cnt[bb];
        if (!n) continue;
        unsigned sb = pos[bb];
        unsigned gb = gbase[bb];
        unsigned capEnd = (unsigned)(bb + 1) * BKT_CAP;
        for (unsigned i = lane; i < n; i += 64) {
            unsigned r = stage[sb + i];
            unsigned slot = gb + i;
            if (slot < capEnd) {
                rec2[slot] = r;
            } else {    // statistically never
                unsigned node = ((unsigned)bb << BKT_SHIFT) | (r & DLOW_MASK);
                atomicAdd(&partial0[node], expand_pkt(r >> 12));
            }
        }
    }
}

// --------------------------------------------------- accum (gather-free) ---
__global__ __launch_bounds__(ACC_THREADS) void tgnn_accum_kernel(
    const unsigned* __restrict__ rec2,
    const unsigned* __restrict__ cursor2,
    unsigned long long* __restrict__ partial)
{
    __shared__ unsigned long long acc[BKT_RANGE];
    int b = blockIdx.x >> 1;            // SPLIT = 2
    int s = blockIdx.x & 1;
    int t = threadIdx.x;

    unsigned count = cursor2[b] - (unsigned)b * BKT_CAP;
    if (count > BKT_CAP) count = BKT_CAP;
    unsigned mid = (count >> 1) & ~3u;
    unsigned i0 = s ? mid : 0u;
    unsigned i1 = s ? count : mid;

    unsigned long long* pb = partial + (size_t)s * NODE_SPACE + (size_t)b * BKT_RANGE;
    if (s == 0) {
        #pragma unroll
        for (int k = 0; k < BKT_RANGE / ACC_THREADS; ++k)
            acc[k * ACC_THREADS + t] = pb[k * ACC_THREADS + t];   // seed ovf
    } else {
        #pragma unroll
        for (int k = 0; k < BKT_RANGE / ACC_THREADS; ++k)
            acc[k * ACC_THREADS + t] = 0ull;
    }
    __syncthreads();

    const unsigned* rb  = rec2 + (size_t)b * BKT_CAP;
    const int4*     rb4 = (const int4*)rb;

    unsigned v0 = i0 >> 2;
    unsigned v1 = i1 >> 2;
    for (unsigned v = v0 + t; v < v1; v += ACC_THREADS) {
        int4 ra = rb4[v];
        unsigned r0 = (unsigned)ra.x, r1 = (unsigned)ra.y;
        unsigned r2 = (unsigned)ra.z, r3 = (unsigned)ra.w;
        atomicAdd(&acc[r0 & DLOW_MASK], expand_pkt(r0 >> 12));
        atomicAdd(&acc[r1 & DLOW_MASK], expand_pkt(r1 >> 12));
        atomicAdd(&acc[r2 & DLOW_MASK], expand_pkt(r2 >> 12));
        atomicAdd(&acc[r3 & DLOW_MASK], expand_pkt(r3 >> 12));
    }
    for (unsigned i = (v1 << 2) + t; i < i1; i += ACC_THREADS) {
        unsigned r = rb[i];
        atomicAdd(&acc[r & DLOW_MASK], expand_pkt(r >> 12));
    }
    __syncthreads();

    #pragma unroll
    for (int k = 0; k < BKT_RANGE / ACC_THREADS; ++k)
        pb[k * ACC_THREADS + t] = acc[k * ACC_THREADS + t];
}

// ---------------------------------------------------------- merge+node -----
__global__ __launch_bounds__(256) void tgnn_merge_node_kernel(
    const float2* __restrict__ nf,
    const unsigned long long* __restrict__ partial,
    const float* __restrict__ P,
    float2* __restrict__ out, int n_nodes)
{
    __shared__ float p[194];
    for (int k = threadIdx.x; k < 194; k += 256) p[k] = P[k];
    __syncthreads();

    int i = blockIdx.x * 256 + threadIdx.x;
    if (i >= n_nodes) return;

    unsigned long long v = partial[i] + partial[NODE_SPACE + i];
    unsigned c = (unsigned)(v >> 52);
    float a0, a1;
    if (c > 0) {
        float inv = 1.0f / (float)c;
        float X = (float)(unsigned)(v & 0x3FFFFFFull);
        float Y = (float)(unsigned)((v >> 26) & 0x3FFFFFFull);
        a0 = X * inv * (1.0f / 64.0f) - 8.0f;
        a1 = Y * inv * (1.0f / 64.0f) - 8.0f;
    } else {
        float2 f = nf[i];
        a0 = f.x;
        a1 = f.y;
    }

    float o0 = p[192], o1 = p[193];
    #pragma unroll
    for (int j = 0; j < 16; ++j) {
        float gr = fmaf(p[j],      a0, fmaf(p[48 + j], a1, p[96 + j]));
        float gz = fmaf(p[16 + j], a0, fmaf(p[64 + j], a1, p[112 + j]));
        float gn = fmaf(p[32 + j], a0, fmaf(p[80 + j], a1, p[128 + j]));
        float r  = 1.0f / (1.0f + __expf(-gr));
        float z  = 1.0f / (1.0f + __expf(-gz));
        float tt = fmaf(r, p[144 + j], gn);
        tt = fminf(fmaxf(tt, -12.0f), 12.0f);
        float e  = __expf(2.0f * tt);
        float n  = (e - 1.0f) / (e + 1.0f);
        float h  = (1.0f - z) * n;
        o0 = fmaf(p[160 + j], h, o0);
        o1 = fmaf(p[176 + j], h, o1);
    }
    out[i] = make_float2(o0, o1);
}

// ----------------------------------------------- fallback (R3 atomic path) --
__global__ __launch_bounds__(256) void tgnn_edge_kernel(
    const unsigned* __restrict__ qnf,
    const int* __restrict__ src,
    const int* __restrict__ dst,
    unsigned long long* __restrict__ pack,
    int n_edges)
{
    int tid    = blockIdx.x * blockDim.x + threadIdx.x;
    int stride = gridDim.x * blockDim.x;
    int n4     = n_edges >> 2;
    const int4* __restrict__ src4 = (const int4*)src;
    const int4* __restrict__ dst4 = (const int4*)dst;
    for (int i = tid; i < n4; i += stride) {
        int4 s = src4[i];
        int4 d = dst4[i];
        unsigned q0 = qnf[s.x], q1 = qnf[s.y], q2 = qnf[s.z], q3 = qnf[s.w];
        atomicAdd(&pack[d.x], expand_pkt(q0));
        atomicAdd(&pack[d.y], expand_pkt(q1));
        atomicAdd(&pack[d.z], expand_pkt(q2));
        atomicAdd(&pack[d.w], expand_pkt(q3));
    }
    for (int e = (n4 << 2) + tid; e < n_edges; e += stride)
        atomicAdd(&pack[dst[e]], expand_pkt(qnf[src[e]]));
}

__global__ __launch_bounds__(256) void tgnn_node_kernel(
    const float2* __restrict__ nf,
    const unsigned long long* __restrict__ pack,
    const float* __restrict__ P,
    float2* __restrict__ out, int n_nodes)
{
    __shared__ float p[194];
    for (int k = threadIdx.x; k < 194; k += 256) p[k] = P[k];
    __syncthreads();
    int i = blockIdx.x * 256 + threadIdx.x;
    if (i >= n_nodes) return;
    unsigned long long v = pack[i];
    unsigned c = (unsigned)(v >> 52);
    float a0, a1;
    if (c > 0) {
        float inv = 1.0f / (float)c;
        float X = (float)(unsigned)(v & 0x3FFFFFFull);
        float Y = (float)(unsigned)((v >> 26) & 0x3FFFFFFull);
        a0 = X * inv * (1.0f / 64.0f) - 8.0f;
        a1 = Y * inv * (1.0f / 64.0f) - 8.0f;
    } else {
        float2 f = nf[i];
        a0 = f.x; a1 = f.y;
    }
    float o0 = p[192], o1 = p[193];
    #pragma unroll
    for (int j = 0; j < 16; ++j) {
        float gr = fmaf(p[j],      a0, fmaf(p[48 + j], a1, p[96 + j]));
        float gz = fmaf(p[16 + j], a0, fmaf(p[64 + j], a1, p[112 + j]));
        float gn = fmaf(p[32 + j], a0, fmaf(p[80 + j], a1, p[128 + j]));
        float r  = 1.0f / (1.0f + __expf(-gr));
        float z  = 1.0f / (1.0f + __expf(-gz));
        float tt = fmaf(r, p[144 + j], gn);
        tt = fminf(fmaxf(tt, -12.0f), 12.0f);
        float e  = __expf(2.0f * tt);
        float n  = (e - 1.0f) / (e + 1.0f);
        float h  = (1.0f - z) * n;
        o0 = fmaf(p[160 + j], h, o0);
        o1 = fmaf(p[176 + j], h, o1);
    }
    out[i] = make_float2(o0, o1);
}

// -------------------------------------------------------------- launch -----
extern "C" void kernel_launch(void* const* d_in, const int* in_sizes, int n_in,
                              void* d_out, int out_size, void* d_ws, size_t ws_size,
                              hipStream_t stream)
{
    const float* nf    = (const float*)d_in[0];
    const int*   ei    = (const int*)d_in[1];
    const float* W_msg = (const float*)d_in[2];
    const float* b_msg = (const float*)d_in[3];
    const float* W_ih  = (const float*)d_in[4];
    const float* b_ih  = (const float*)d_in[6];
    const float* b_hh  = (const float*)d_in[7];
    const float* W_cls = (const float*)d_in[8];
    const float* b_cls = (const float*)d_in[9];
    float* out = (float*)d_out;

    const int N = in_sizes[0] / 2;
    const int E = in_sizes[1] / 2;
    const int qBlocks = (N + 255) / 256;

    size_t off = 0;
    auto take = [&](size_t bytes) { size_t o = off; off = (off + bytes + 255) & ~(size_t)255; return o; };
    size_t partialOff = take((size_t)SPLIT * NODE_SPACE * 8);   // 16.8 MB
    size_t rec1Off    = take((size_t)NBKT * BKT_CAP * 4);       // 142.6 MB
    size_t rec2Off    = take((size_t)NBKT * BKT_CAP * 4);       // 142.6 MB
    size_t qnfOff     = take((size_t)N * 4);                    // 4 MB
    size_t cur1Off    = take((size_t)NBKT * 4);
    size_t cur2Off    = take((size_t)NBKT * 4);
    size_t pOff       = take(194 * 4);
    size_t need = off;                                          // ~306 MB

    char* ws = (char*)d_ws;

    if (ws_size >= need) {
        unsigned long long* partial = (unsigned long long*)(ws + partialOff);
        unsigned* rec1    = (unsigned*)(ws + rec1Off);
        unsigned* rec2    = (unsigned*)(ws + rec2Off);
        unsigned* qnf     = (unsigned*)(ws + qnfOff);
        unsigned* cursor1 = (unsigned*)(ws + cur1Off);
        unsigned* cursor2 = (unsigned*)(ws + cur2Off);
        float*    P       = (float*)(ws + pOff);

        // zero partial slice 0 (overflow target / accum seed)
        (void)hipMemsetAsync(partial, 0, (size_t)NODE_SPACE * 8, stream);

        tgnn_prep_kernel<<<1, 256, 0, stream>>>(W_msg, b_msg, W_ih, b_ih, b_hh,
                                                W_cls, b_cls, P, cursor1, cursor2);
        tgnn_quant_kernel<<<qBlocks, 256, 0, stream>>>((const float2*)nf, qnf, N);

        int binBlocks = (E + CHUNK - 1) / CHUNK;
        tgnn_bin1_kernel<<<binBlocks, BIN_THREADS, 0, stream>>>(ei, ei + E, qnf,
                                                                rec1, cursor1,
                                                                partial, E);

        dim3 g2(SLICES2, NBKT);
        tgnn_pass2_kernel<<<g2, 256, 0, stream>>>(rec1, cursor1, qnf,
                                                  rec2, cursor2, partial);

        tgnn_accum_kernel<<<NBKT * SPLIT, ACC_THREADS, 0, stream>>>(rec2, cursor2,
                                                                    partial);

        tgnn_merge_node_kernel<<<qBlocks, 256, 0, stream>>>((const float2*)nf, partial,
                                                            P, (float2*)out, N);
    } else {
        // fallback: one-atomic-per-edge path (needs ~12N bytes)
        unsigned long long* pack = (unsigned long long*)ws;
        unsigned* qnf = (unsigned*)(ws + (size_t)N * 8);
        float*    P   = (float*)(ws + (size_t)N * 12);
        unsigned* curD1 = (unsigned*)(ws + (size_t)N * 12 + 1024);
        unsigned* curD2 = (unsigned*)(ws + (size_t)N * 12 + 3072);

        (void)hipMemsetAsync(pack, 0, (size_t)N * 8, stream);
        tgnn_prep_kernel<<<1, 256, 0, stream>>>(W_msg, b_msg, W_ih, b_ih, b_hh,
                                                W_cls, b_cls, P, curD1, curD2);
        tgnn_quant_kernel<<<qBlocks, 256, 0, stream>>>((const float2*)nf, qnf, N);
        tgnn_edge_kernel<<<2048, 256, 0, stream>>>(qnf, ei, ei + E, pack, E);
        tgnn_node_kernel<<<qBlocks, 256, 0, stream>>>((const float2*)nf, pack,
                                                      P, (float2*)out, N);
    }
}